// Round 1
// baseline (2173.566 us; speedup 1.0000x reference)
//
#include <hip/hip_runtime.h>
#include <math.h>

// EdgeEvidenceHead fused kernel — fp32 vector baseline (round 1).
//
// Shapes (fixed by reference):
//   z[100000][128] f32, edge_index[2][500000] int, extra[500000][5] f32,
//   W1[519][256] f32, b1[256], W2[256][2], b2[2], out[500000][2] f32.
//
// Strategy: fused per-edge feature build + GEMM1(519->256) + ReLU + GEMM2(256->2)
// + softplus. M_tile=32 edges/block, K chunked by 32, all 256 outputs per block.
// No fp32 MFMA on CDNA4 -> vector FMA path; floor = 133 GFLOP / 157 TF = 0.85 ms.

#define HIDDEN   128
#define EHID     256
#define NEDGES   500000
#define NNODES   100000
#define MT       32      // edges per block
#define KT       32      // K chunk
#define PAD      36      // padded edge-stride for transposed LDS tiles (144B, 16B-aligned)
#define NTHREADS 256

__device__ __forceinline__ float softplus_f(float x) {
    // log1p(exp(x)) stable form; matches jax.nn.softplus within fp32 tolerance
    return fmaxf(x, 0.0f) + log1pf(expf(-fabsf(x)));
}

__global__ __launch_bounds__(NTHREADS, 2)
void edge_evidence_kernel(const float* __restrict__ z,
                          const int*   __restrict__ eidx,
                          const float* __restrict__ extra,
                          const float* __restrict__ W1,
                          const float* __restrict__ b1,
                          const float* __restrict__ W2,
                          const float* __restrict__ b2,
                          float* __restrict__ out)
{
    // smemA rows (each PAD floats wide, indexed [row][edge]):
    //   [0,128)   : z_u transposed
    //   [128,256) : z_v transposed   (feature row k in [128,256) == smemA row k: free remap)
    //   [256,288) : A-chunk staging for abs/prod/tail chunks
    __shared__ float smemA[288 * PAD];
    __shared__ float Bch[KT][EHID];
    __shared__ int   su[MT], sv[MT];
    __shared__ float sdot[MT], scos[MT];

    const int t  = threadIdx.x;
    const int e0 = blockIdx.x * MT;
    const int tn = t & 31;   // output-col group: cols [tn*8, tn*8+8)
    const int tm = t >> 5;   // edge group: edges [tm*4, tm*4+4)

    if (t < MT)          su[t]      = eidx[e0 + t];
    else if (t < 2 * MT) sv[t - MT] = eidx[NEDGES + e0 + (t - MT)];
    __syncthreads();

    // ---- gather z_u/z_v (transposed into LDS) + fused dot/norm/cos ----
    // 32 consecutive threads cover one edge's full 128 dims (one float4 each),
    // so dot/||u||/||v|| reduce with 5 shfl_xor steps inside a half-wave.
    {
        const int c4 = t & 31;   // float4 index within the 128-dim row
        const int eb = t >> 5;   // base edge 0..7
        for (int r = 0; r < 4; ++r) {
            const int e = eb + 8 * r;
            const float4 a = *reinterpret_cast<const float4*>(&z[(size_t)su[e] * HIDDEN + c4 * 4]);
            const float4 b = *reinterpret_cast<const float4*>(&z[(size_t)sv[e] * HIDDEN + c4 * 4]);
            const int k0 = c4 * 4;
            smemA[(k0 + 0) * PAD + e] = a.x;
            smemA[(k0 + 1) * PAD + e] = a.y;
            smemA[(k0 + 2) * PAD + e] = a.z;
            smemA[(k0 + 3) * PAD + e] = a.w;
            smemA[(HIDDEN + k0 + 0) * PAD + e] = b.x;
            smemA[(HIDDEN + k0 + 1) * PAD + e] = b.y;
            smemA[(HIDDEN + k0 + 2) * PAD + e] = b.z;
            smemA[(HIDDEN + k0 + 3) * PAD + e] = b.w;
            float d  = a.x*b.x + a.y*b.y + a.z*b.z + a.w*b.w;
            float nu = a.x*a.x + a.y*a.y + a.z*a.z + a.w*a.w;
            float nv = b.x*b.x + b.y*b.y + b.z*b.z + b.w*b.w;
            #pragma unroll
            for (int m = 16; m >= 1; m >>= 1) {
                d  += __shfl_xor(d,  m);
                nu += __shfl_xor(nu, m);
                nv += __shfl_xor(nv, m);
            }
            if (c4 == 0) {
                sdot[e] = d;
                const float nn = fmaxf(sqrtf(nu), 1e-12f) * fmaxf(sqrtf(nv), 1e-12f);
                scos[e] = d / nn;
            }
        }
    }

    float acc[4][8];
    #pragma unroll
    for (int i = 0; i < 4; ++i)
        #pragma unroll
        for (int j = 0; j < 8; ++j) acc[i][j] = 0.0f;

    // ---- K loop: 16 chunks of 32 + tail of 7 (dot, cos, extra[5]) ----
    for (int kc = 0; kc < 17; ++kc) {
        const int kbase = kc * KT;
        const int krows = (kc == 16) ? 7 : KT;

        __syncthreads();   // previous compute done (first iter: gather done)

        // stage W1 chunk -> Bch (coalesced float4, L2-resident source)
        for (int i = t; i < krows * (EHID / 4); i += NTHREADS) {
            const int kk = i >> 6;          // /64 f4-per-row
            const int c  = i & 63;
            *reinterpret_cast<float4*>(&Bch[kk][c * 4]) =
                *reinterpret_cast<const float4*>(&W1[(size_t)(kbase + kk) * EHID + c * 4]);
        }

        // A source row base inside smemA
        int arow0;
        if (kc < 8) {
            arow0 = kbase;                   // z_u rows [0,128) then z_v rows [128,256)
        } else if (kc < 16) {
            const int off = kbase - (kc < 12 ? 256 : 384);  // row within z tiles
            for (int i = t; i < KT * MT; i += NTHREADS) {
                const int kk = i >> 5, e = i & 31;
                const float xu = smemA[(off + kk) * PAD + e];
                const float xv = smemA[(HIDDEN + off + kk) * PAD + e];
                smemA[(256 + kk) * PAD + e] = (kc < 12) ? fabsf(xu - xv) : (xu * xv);
            }
            arow0 = 256;
        } else {
            // tail rows: 0=dot, 1=cos, 2..6=extra
            if (t < MT) {
                smemA[(256 + 0) * PAD + t] = sdot[t];
                smemA[(256 + 1) * PAD + t] = scos[t];
            }
            for (int i = t; i < MT * 5; i += NTHREADS) {
                const int e = i / 5, x = i % 5;
                smemA[(256 + 2 + x) * PAD + e] = extra[(size_t)(e0 + e) * 5 + x];
            }
            arow0 = 256;
        }

        __syncthreads();

        // ---- FMA inner loop: 3x ds_read_b128 + 32 v_fma_f32 per k ----
        #pragma unroll 4
        for (int k = 0; k < krows; ++k) {
            float a[4], b[8];
            *reinterpret_cast<float4*>(a)     = *reinterpret_cast<const float4*>(&smemA[(arow0 + k) * PAD + tm * 4]);
            *reinterpret_cast<float4*>(&b[0]) = *reinterpret_cast<const float4*>(&Bch[k][tn * 8]);
            *reinterpret_cast<float4*>(&b[4]) = *reinterpret_cast<const float4*>(&Bch[k][tn * 8 + 4]);
            #pragma unroll
            for (int i = 0; i < 4; ++i)
                #pragma unroll
                for (int j = 0; j < 8; ++j)
                    acc[i][j] = fmaf(a[i], b[j], acc[i][j]);
        }
    }

    // ---- epilogue: bias + ReLU, GEMM2 (256->2), softplus ----
    float b1v[8], w2a[8], w2b[8];
    *reinterpret_cast<float4*>(&b1v[0]) = *reinterpret_cast<const float4*>(&b1[tn * 8]);
    *reinterpret_cast<float4*>(&b1v[4]) = *reinterpret_cast<const float4*>(&b1[tn * 8 + 4]);
    #pragma unroll
    for (int j = 0; j < 8; ++j) {
        w2a[j] = W2[(tn * 8 + j) * 2 + 0];
        w2b[j] = W2[(tn * 8 + j) * 2 + 1];
    }
    const float bb0 = b2[0], bb1 = b2[1];

    #pragma unroll
    for (int i = 0; i < 4; ++i) {
        float p0 = 0.0f, p1 = 0.0f;
        #pragma unroll
        for (int j = 0; j < 8; ++j) {
            const float h = fmaxf(acc[i][j] + b1v[j], 0.0f);
            p0 = fmaf(h, w2a[j], p0);
            p1 = fmaf(h, w2b[j], p1);
        }
        #pragma unroll
        for (int m = 16; m >= 1; m >>= 1) {
            p0 += __shfl_xor(p0, m);
            p1 += __shfl_xor(p1, m);
        }
        if (tn == 0) {
            const int e = e0 + tm * 4 + i;
            out[(size_t)e * 2 + 0] = softplus_f(p0 + bb0);
            out[(size_t)e * 2 + 1] = softplus_f(p1 + bb1);
        }
    }
}

extern "C" void kernel_launch(void* const* d_in, const int* in_sizes, int n_in,
                              void* d_out, int out_size, void* d_ws, size_t ws_size,
                              hipStream_t stream) {
    const float* z     = (const float*)d_in[0];
    const int*   eidx  = (const int*)  d_in[1];   // harness contract: integer -> const int*
    const float* extra = (const float*)d_in[2];
    const float* W1    = (const float*)d_in[3];
    const float* b1    = (const float*)d_in[4];
    const float* W2    = (const float*)d_in[5];
    const float* b2    = (const float*)d_in[6];
    float* out = (float*)d_out;

    const int nblocks = NEDGES / MT;   // 500000/32 = 15625 exactly, no tail
    edge_evidence_kernel<<<dim3(nblocks), dim3(NTHREADS), 0, stream>>>(
        z, eidx, extra, W1, b1, W2, b2, out);
}